// Round 1
// baseline (652.908 us; speedup 1.0000x reference)
//
#include <hip/hip_runtime.h>
#include <stdint.h>

#define LN_EPS 1e-5f

// async global->LDS, 16B per lane; LDS dest is wave-uniform base + lane*16
__device__ __forceinline__ void gld_lds16(const void* g, void* l) {
  __builtin_amdgcn_global_load_lds(
      (const __attribute__((address_space(1))) uint32_t*)(uintptr_t)g,
      (__attribute__((address_space(3))) uint32_t*)(uintptr_t)l,
      16, 0, 0);
}

// block = 128 threads = 2 waves; each wave: 64 rows, one row per lane.
__global__ __launch_bounds__(128) void dec_kernel(
    const float* __restrict__ x,
    const float* __restrict__ w1, const float* __restrict__ g1, const float* __restrict__ b1,
    const float* __restrict__ w2, const float* __restrict__ g2, const float* __restrict__ b2,
    const float* __restrict__ w3, const float* __restrict__ b3,
    float* __restrict__ out, int N, int HW)
{
  // per-wave 16KB tile: 64 rows x 16 chunks of 16B, chunk-rotated storage
  __shared__ float4 tile[2][1024];
  const int tid  = threadIdx.x;
  const int wv   = tid >> 6;
  const int lane = tid & 63;
  const int row0 = (blockIdx.x * 2 + wv) << 6;
  if (row0 >= N) return;

  // ---- stage: 16 x global_load_lds_dwordx4, each 1KB coalesced ----
  {
    const int rsub = lane >> 4;   // row within 4-row group
    const int m    = lane & 15;   // LDS slot chunk index
#pragma unroll
    for (int t = 0; t < 16; ++t) {
      int r  = t * 4 + rsub;               // slot row 0..63
      int rg = row0 + r; if (rg > N - 1) rg = N - 1;
      int c  = (m - r) & 15;               // which global chunk goes in slot m
      const float* gp = x + (size_t)rg * 64 + (c << 2);
      gld_lds16((const void*)gp, (void*)&tile[wv][t * 64]);
    }
  }
  __builtin_amdgcn_s_waitcnt(0x0F70);  // vmcnt(0); exp/lgkm don't-care
  __asm__ volatile("" ::: "memory");

  // ---- layer 1: h1 = relu(LN(x @ w1)), K=64 -> 32 ----
  float acc[32];
#pragma unroll
  for (int j = 0; j < 32; ++j) acc[j] = 0.f;

  const float4* myrow = &tile[wv][lane << 4];
#pragma unroll
  for (int c = 0; c < 16; ++c) {
    // rotated read: slot (c+lane)&15 holds chunk c -> uniform k order
    float4 xv = myrow[(c + lane) & 15];
#pragma unroll
    for (int kk = 0; kk < 4; ++kk) {
      float xk = (kk == 0) ? xv.x : (kk == 1) ? xv.y : (kk == 2) ? xv.z : xv.w;
      const float* wrow = w1 + (c * 4 + kk) * 32;  // uniform -> s_load
#pragma unroll
      for (int j = 0; j < 32; ++j) acc[j] = fmaf(xk, wrow[j], acc[j]);
    }
  }

  // LayerNorm(32) + ReLU
  {
    float p0 = 0.f, p1 = 0.f, p2 = 0.f, p3 = 0.f;
#pragma unroll
    for (int j = 0; j < 32; j += 4) { p0 += acc[j]; p1 += acc[j+1]; p2 += acc[j+2]; p3 += acc[j+3]; }
    float mu = ((p0 + p1) + (p2 + p3)) * 0.03125f;
    float q0 = 0.f, q1 = 0.f, q2 = 0.f, q3 = 0.f;
#pragma unroll
    for (int j = 0; j < 32; j += 4) {
      float d0 = acc[j] - mu, d1 = acc[j+1] - mu, d2 = acc[j+2] - mu, d3 = acc[j+3] - mu;
      acc[j] = d0; acc[j+1] = d1; acc[j+2] = d2; acc[j+3] = d3;
      q0 = fmaf(d0, d0, q0); q1 = fmaf(d1, d1, q1); q2 = fmaf(d2, d2, q2); q3 = fmaf(d3, d3, q3);
    }
    float var = ((q0 + q1) + (q2 + q3)) * 0.03125f;
    float rs  = rsqrtf(var + LN_EPS);
#pragma unroll
    for (int j = 0; j < 32; ++j) {
      float t = acc[j] * rs;
      t = fmaf(t, g1[j], b1[j]);
      acc[j] = fmaxf(t, 0.f);
    }
  }

  // ---- layer 2: h2 = relu(LN(h1 @ w2)), K=32 -> 16 ----
  float a2[16];
#pragma unroll
  for (int j = 0; j < 16; ++j) a2[j] = 0.f;
#pragma unroll
  for (int k = 0; k < 32; ++k) {
    float hk = acc[k];
    const float* wrow = w2 + k * 16;
#pragma unroll
    for (int j = 0; j < 16; ++j) a2[j] = fmaf(hk, wrow[j], a2[j]);
  }
  {
    float p0 = 0.f, p1 = 0.f, p2 = 0.f, p3 = 0.f;
#pragma unroll
    for (int j = 0; j < 16; j += 4) { p0 += a2[j]; p1 += a2[j+1]; p2 += a2[j+2]; p3 += a2[j+3]; }
    float mu = ((p0 + p1) + (p2 + p3)) * 0.0625f;
    float q0 = 0.f, q1 = 0.f, q2 = 0.f, q3 = 0.f;
#pragma unroll
    for (int j = 0; j < 16; j += 4) {
      float d0 = a2[j] - mu, d1 = a2[j+1] - mu, d2 = a2[j+2] - mu, d3 = a2[j+3] - mu;
      a2[j] = d0; a2[j+1] = d1; a2[j+2] = d2; a2[j+3] = d3;
      q0 = fmaf(d0, d0, q0); q1 = fmaf(d1, d1, q1); q2 = fmaf(d2, d2, q2); q3 = fmaf(d3, d3, q3);
    }
    float var = ((q0 + q1) + (q2 + q3)) * 0.0625f;
    float rs  = rsqrtf(var + LN_EPS);
#pragma unroll
    for (int j = 0; j < 16; ++j) {
      float t = a2[j] * rs;
      t = fmaf(t, g2[j], b2[j]);
      a2[j] = fmaxf(t, 0.f);
    }
  }

  // ---- layer 3: out3 = h2 @ w3 + b3, then L2-normalize over the 3 channels ----
  float o0 = b3[0], o1 = b3[1], o2 = b3[2];
#pragma unroll
  for (int k = 0; k < 16; ++k) {
    float hk = a2[k];
    o0 = fmaf(hk, w3[k * 3 + 0], o0);
    o1 = fmaf(hk, w3[k * 3 + 1], o1);
    o2 = fmaf(hk, w3[k * 3 + 2], o2);
  }
  float nsq = fmaf(o0, o0, fmaf(o1, o1, o2 * o2));
  // 1/max(||o||, 1e-12) == rsqrt(max(nsq, 1e-24))
  float inv = rsqrtf(fmaxf(nsq, 1e-24f));
  o0 *= inv; o1 *= inv; o2 *= inv;

  const int row = row0 + lane;
  if (row < N) {
    // out[b][c][h][w]; flat = b*3*HW + c*HW + p
    int b = (int)((unsigned)row / (unsigned)HW);
    int p = row - b * HW;
    size_t obase = (size_t)b * 3 * HW + p;
    out[obase]            = o0;
    out[obase + HW]       = o1;
    out[obase + 2 * HW]   = o2;
  }
}

extern "C" void kernel_launch(void* const* d_in, const int* in_sizes, int n_in,
                              void* d_out, int out_size, void* d_ws, size_t ws_size,
                              hipStream_t stream) {
  const float* x  = (const float*)d_in[0];
  const float* w1 = (const float*)d_in[1];
  const float* g1 = (const float*)d_in[2];
  const float* b1 = (const float*)d_in[3];
  const float* w2 = (const float*)d_in[4];
  const float* g2 = (const float*)d_in[5];
  const float* b2 = (const float*)d_in[6];
  const float* w3 = (const float*)d_in[7];
  const float* b3 = (const float*)d_in[8];
  float* out = (float*)d_out;

  const int N  = in_sizes[0] / 64;  // rows
  const int HW = N / 4;             // B = 4 per reference setup
  const int nblocks = (N + 127) / 128;  // 2 waves/block, 64 rows/wave
  dec_kernel<<<nblocks, 128, 0, stream>>>(x, w1, g1, b1, w2, g2, b2, w3, b3, out, N, HW);
}

// Round 2
// 613.816 us; speedup vs baseline: 1.0637x; 1.0637x over previous
//
#include <hip/hip_runtime.h>
#include <stdint.h>

#define LN_EPS 1e-5f

// block = 256 threads; one row per lane, direct global loads (no LDS).
// __launch_bounds__(256, 5): 5 waves/SIMD -> 20 waves/CU, VGPR cap ~102.
__global__ __launch_bounds__(256, 5) void dec_kernel(
    const float* __restrict__ x,
    const float* __restrict__ w1, const float* __restrict__ g1, const float* __restrict__ b1,
    const float* __restrict__ w2, const float* __restrict__ g2, const float* __restrict__ b2,
    const float* __restrict__ w3, const float* __restrict__ b3,
    float* __restrict__ out, int N, int HW)
{
  const int row = blockIdx.x * 256 + threadIdx.x;
  if (row >= N) return;

  // ---- layer 1: h1 = relu(LN(x @ w1)), K=64 -> 32 ----
  const float4* __restrict__ xp = (const float4*)(x + (size_t)row * 64);

  float acc[32];
#pragma unroll
  for (int j = 0; j < 32; ++j) acc[j] = 0.f;

#pragma unroll
  for (int c = 0; c < 16; ++c) {
    float4 xv = xp[c];                       // global_load_dwordx4, imm offset c*16
#pragma unroll
    for (int kk = 0; kk < 4; ++kk) {
      float xk = (kk == 0) ? xv.x : (kk == 1) ? xv.y : (kk == 2) ? xv.z : xv.w;
      const float* wrow = w1 + (c * 4 + kk) * 32;   // wave-uniform -> s_load
#pragma unroll
      for (int j = 0; j < 32; ++j) acc[j] = fmaf(xk, wrow[j], acc[j]);
    }
  }

  // LayerNorm(32) + ReLU
  {
    float p0 = 0.f, p1 = 0.f, p2 = 0.f, p3 = 0.f;
#pragma unroll
    for (int j = 0; j < 32; j += 4) { p0 += acc[j]; p1 += acc[j+1]; p2 += acc[j+2]; p3 += acc[j+3]; }
    float mu = ((p0 + p1) + (p2 + p3)) * 0.03125f;
    float q0 = 0.f, q1 = 0.f, q2 = 0.f, q3 = 0.f;
#pragma unroll
    for (int j = 0; j < 32; j += 4) {
      float d0 = acc[j] - mu, d1 = acc[j+1] - mu, d2 = acc[j+2] - mu, d3 = acc[j+3] - mu;
      acc[j] = d0; acc[j+1] = d1; acc[j+2] = d2; acc[j+3] = d3;
      q0 = fmaf(d0, d0, q0); q1 = fmaf(d1, d1, q1); q2 = fmaf(d2, d2, q2); q3 = fmaf(d3, d3, q3);
    }
    float var = ((q0 + q1) + (q2 + q3)) * 0.03125f;
    float rs  = rsqrtf(var + LN_EPS);
#pragma unroll
    for (int j = 0; j < 32; ++j) {
      float t = acc[j] * rs;
      t = fmaf(t, g1[j], b1[j]);
      acc[j] = fmaxf(t, 0.f);
    }
  }

  // ---- layer 2: h2 = relu(LN(h1 @ w2)), K=32 -> 16 ----
  float a2[16];
#pragma unroll
  for (int j = 0; j < 16; ++j) a2[j] = 0.f;
#pragma unroll
  for (int k = 0; k < 32; ++k) {
    float hk = acc[k];
    const float* wrow = w2 + k * 16;         // wave-uniform -> s_load
#pragma unroll
    for (int j = 0; j < 16; ++j) a2[j] = fmaf(hk, wrow[j], a2[j]);
  }
  {
    float p0 = 0.f, p1 = 0.f, p2 = 0.f, p3 = 0.f;
#pragma unroll
    for (int j = 0; j < 16; j += 4) { p0 += a2[j]; p1 += a2[j+1]; p2 += a2[j+2]; p3 += a2[j+3]; }
    float mu = ((p0 + p1) + (p2 + p3)) * 0.0625f;
    float q0 = 0.f, q1 = 0.f, q2 = 0.f, q3 = 0.f;
#pragma unroll
    for (int j = 0; j < 16; j += 4) {
      float d0 = a2[j] - mu, d1 = a2[j+1] - mu, d2 = a2[j+2] - mu, d3 = a2[j+3] - mu;
      a2[j] = d0; a2[j+1] = d1; a2[j+2] = d2; a2[j+3] = d3;
      q0 = fmaf(d0, d0, q0); q1 = fmaf(d1, d1, q1); q2 = fmaf(d2, d2, q2); q3 = fmaf(d3, d3, q3);
    }
    float var = ((q0 + q1) + (q2 + q3)) * 0.0625f;
    float rs  = rsqrtf(var + LN_EPS);
#pragma unroll
    for (int j = 0; j < 16; ++j) {
      float t = a2[j] * rs;
      t = fmaf(t, g2[j], b2[j]);
      a2[j] = fmaxf(t, 0.f);
    }
  }

  // ---- layer 3: out3 = h2 @ w3 + b3, then L2-normalize over the 3 channels ----
  float o0 = b3[0], o1 = b3[1], o2 = b3[2];
#pragma unroll
  for (int k = 0; k < 16; ++k) {
    float hk = a2[k];
    o0 = fmaf(hk, w3[k * 3 + 0], o0);
    o1 = fmaf(hk, w3[k * 3 + 1], o1);
    o2 = fmaf(hk, w3[k * 3 + 2], o2);
  }
  float nsq = fmaf(o0, o0, fmaf(o1, o1, o2 * o2));
  // 1/max(||o||, 1e-12) == rsqrt(max(nsq, 1e-24))
  float inv = rsqrtf(fmaxf(nsq, 1e-24f));
  o0 *= inv; o1 *= inv; o2 *= inv;

  // out[b][c][h][w]; flat = b*3*HW + c*HW + p; lanes are consecutive in p -> coalesced
  int b = (int)((unsigned)row / (unsigned)HW);
  int p = row - b * HW;
  size_t obase = (size_t)b * 3 * HW + p;
  out[obase]          = o0;
  out[obase + HW]     = o1;
  out[obase + 2 * HW] = o2;
}

extern "C" void kernel_launch(void* const* d_in, const int* in_sizes, int n_in,
                              void* d_out, int out_size, void* d_ws, size_t ws_size,
                              hipStream_t stream) {
  const float* x  = (const float*)d_in[0];
  const float* w1 = (const float*)d_in[1];
  const float* g1 = (const float*)d_in[2];
  const float* b1 = (const float*)d_in[3];
  const float* w2 = (const float*)d_in[4];
  const float* g2 = (const float*)d_in[5];
  const float* b2 = (const float*)d_in[6];
  const float* w3 = (const float*)d_in[7];
  const float* b3 = (const float*)d_in[8];
  float* out = (float*)d_out;

  const int N  = in_sizes[0] / 64;  // rows
  const int HW = N / 4;             // B = 4 per reference setup
  const int nblocks = (N + 255) / 256;
  dec_kernel<<<nblocks, 256, 0, stream>>>(x, w1, g1, b1, w2, g2, b2, w3, b3, out, N, HW);
}

// Round 3
// 575.257 us; speedup vs baseline: 1.1350x; 1.0670x over previous
//
#include <hip/hip_runtime.h>
#include <stdint.h>

#define LN_EPS 1e-5f

// block = 256 threads; one row per lane. Whole 256B row is batch-prefetched
// into 16 float4 registers so all 16 global_load_dwordx4 issue back-to-back:
// one latency exposure per wave, and the 64B-line reuse window collapses from
// ~27k cyc (L2-evicting, 1.86x HBM over-fetch measured in R2) to ~30 cyc.
// __launch_bounds__(256, 4): VGPR cap 128 (need ~64 xv + 32 acc + temps).
__global__ __launch_bounds__(256, 4) void dec_kernel(
    const float* __restrict__ x,
    const float* __restrict__ w1, const float* __restrict__ g1, const float* __restrict__ b1,
    const float* __restrict__ w2, const float* __restrict__ g2, const float* __restrict__ b2,
    const float* __restrict__ w3, const float* __restrict__ b3,
    float* __restrict__ out, int N, int HW)
{
  const int row = blockIdx.x * 256 + threadIdx.x;
  if (row >= N) return;

  const float4* __restrict__ xp = (const float4*)(x + (size_t)row * 64);

  // ---- batch prefetch: 16 back-to-back dwordx4, fine-grained vmcnt on use ----
  float4 xv[16];
#pragma unroll
  for (int c = 0; c < 16; ++c) xv[c] = xp[c];

  // ---- layer 1: h1 = relu(LN(x @ w1)), K=64 -> 32 ----
  float acc[32];
#pragma unroll
  for (int j = 0; j < 32; ++j) acc[j] = 0.f;

#pragma unroll
  for (int c = 0; c < 16; ++c) {
#pragma unroll
    for (int kk = 0; kk < 4; ++kk) {
      float xk = (kk == 0) ? xv[c].x : (kk == 1) ? xv[c].y : (kk == 2) ? xv[c].z : xv[c].w;
      const float* wrow = w1 + (c * 4 + kk) * 32;   // wave-uniform -> s_load
#pragma unroll
      for (int j = 0; j < 32; ++j) acc[j] = fmaf(xk, wrow[j], acc[j]);
    }
  }

  // LayerNorm(32) + ReLU
  {
    float p0 = 0.f, p1 = 0.f, p2 = 0.f, p3 = 0.f;
#pragma unroll
    for (int j = 0; j < 32; j += 4) { p0 += acc[j]; p1 += acc[j+1]; p2 += acc[j+2]; p3 += acc[j+3]; }
    float mu = ((p0 + p1) + (p2 + p3)) * 0.03125f;
    float q0 = 0.f, q1 = 0.f, q2 = 0.f, q3 = 0.f;
#pragma unroll
    for (int j = 0; j < 32; j += 4) {
      float d0 = acc[j] - mu, d1 = acc[j+1] - mu, d2 = acc[j+2] - mu, d3 = acc[j+3] - mu;
      acc[j] = d0; acc[j+1] = d1; acc[j+2] = d2; acc[j+3] = d3;
      q0 = fmaf(d0, d0, q0); q1 = fmaf(d1, d1, q1); q2 = fmaf(d2, d2, q2); q3 = fmaf(d3, d3, q3);
    }
    float var = ((q0 + q1) + (q2 + q3)) * 0.03125f;
    float rs  = rsqrtf(var + LN_EPS);
#pragma unroll
    for (int j = 0; j < 32; ++j) {
      float t = acc[j] * rs;
      t = fmaf(t, g1[j], b1[j]);
      acc[j] = fmaxf(t, 0.f);
    }
  }

  // ---- layer 2: h2 = relu(LN(h1 @ w2)), K=32 -> 16 ----
  float a2[16];
#pragma unroll
  for (int j = 0; j < 16; ++j) a2[j] = 0.f;
#pragma unroll
  for (int k = 0; k < 32; ++k) {
    float hk = acc[k];
    const float* wrow = w2 + k * 16;         // wave-uniform -> s_load
#pragma unroll
    for (int j = 0; j < 16; ++j) a2[j] = fmaf(hk, wrow[j], a2[j]);
  }
  {
    float p0 = 0.f, p1 = 0.f, p2 = 0.f, p3 = 0.f;
#pragma unroll
    for (int j = 0; j < 16; j += 4) { p0 += a2[j]; p1 += a2[j+1]; p2 += a2[j+2]; p3 += a2[j+3]; }
    float mu = ((p0 + p1) + (p2 + p3)) * 0.0625f;
    float q0 = 0.f, q1 = 0.f, q2 = 0.f, q3 = 0.f;
#pragma unroll
    for (int j = 0; j < 16; j += 4) {
      float d0 = a2[j] - mu, d1 = a2[j+1] - mu, d2 = a2[j+2] - mu, d3 = a2[j+3] - mu;
      a2[j] = d0; a2[j+1] = d1; a2[j+2] = d2; a2[j+3] = d3;
      q0 = fmaf(d0, d0, q0); q1 = fmaf(d1, d1, q1); q2 = fmaf(d2, d2, q2); q3 = fmaf(d3, d3, q3);
    }
    float var = ((q0 + q1) + (q2 + q3)) * 0.0625f;
    float rs  = rsqrtf(var + LN_EPS);
#pragma unroll
    for (int j = 0; j < 16; ++j) {
      float t = a2[j] * rs;
      t = fmaf(t, g2[j], b2[j]);
      a2[j] = fmaxf(t, 0.f);
    }
  }

  // ---- layer 3: out3 = h2 @ w3 + b3, then L2-normalize over the 3 channels ----
  float o0 = b3[0], o1 = b3[1], o2 = b3[2];
#pragma unroll
  for (int k = 0; k < 16; ++k) {
    float hk = a2[k];
    o0 = fmaf(hk, w3[k * 3 + 0], o0);
    o1 = fmaf(hk, w3[k * 3 + 1], o1);
    o2 = fmaf(hk, w3[k * 3 + 2], o2);
  }
  float nsq = fmaf(o0, o0, fmaf(o1, o1, o2 * o2));
  // 1/max(||o||, 1e-12) == rsqrt(max(nsq, 1e-24))
  float inv = rsqrtf(fmaxf(nsq, 1e-24f));
  o0 *= inv; o1 *= inv; o2 *= inv;

  // out[b][c][h][w]; flat = b*3*HW + c*HW + p; lanes are consecutive in p -> coalesced
  int b = (int)((unsigned)row / (unsigned)HW);
  int p = row - b * HW;
  size_t obase = (size_t)b * 3 * HW + p;
  out[obase]          = o0;
  out[obase + HW]     = o1;
  out[obase + 2 * HW] = o2;
}

extern "C" void kernel_launch(void* const* d_in, const int* in_sizes, int n_in,
                              void* d_out, int out_size, void* d_ws, size_t ws_size,
                              hipStream_t stream) {
  const float* x  = (const float*)d_in[0];
  const float* w1 = (const float*)d_in[1];
  const float* g1 = (const float*)d_in[2];
  const float* b1 = (const float*)d_in[3];
  const float* w2 = (const float*)d_in[4];
  const float* g2 = (const float*)d_in[5];
  const float* b2 = (const float*)d_in[6];
  const float* w3 = (const float*)d_in[7];
  const float* b3 = (const float*)d_in[8];
  float* out = (float*)d_out;

  const int N  = in_sizes[0] / 64;  // rows
  const int HW = N / 4;             // B = 4 per reference setup
  const int nblocks = (N + 255) / 256;
  dec_kernel<<<nblocks, 256, 0, stream>>>(x, w1, g1, b1, w2, g2, b2, w3, b3, out, N, HW);
}